// Round 3
// baseline (639.333 us; speedup 1.0000x reference)
//
#include <hip/hip_runtime.h>
#include <cstdint>
#include <cstddef>

#define CH 128
#define BM 64          // edges per k2 block (256 threads, 4 waves)

typedef __attribute__((ext_vector_type(8))) short bf16x8;
typedef __attribute__((ext_vector_type(4))) float f32x4;

__device__ __forceinline__ unsigned short f2bf(float x){
    unsigned int u = __float_as_uint(x);
    u = (u + 0x7FFFu + ((u >> 16) & 1u)) >> 16;   // RNE
    return (unsigned short)u;
}
__device__ __forceinline__ float bf2f(unsigned short b){
    return __uint_as_float(((unsigned int)b) << 16);
}
__device__ __forceinline__ unsigned int pairadd_bf(unsigned int a, unsigned int b){
    float lo = bf2f((unsigned short)(a & 0xffff)) + bf2f((unsigned short)(b & 0xffff));
    float hi = bf2f((unsigned short)(a >> 16))    + bf2f((unsigned short)(b >> 16));
    return (unsigned int)f2bf(lo) | ((unsigned int)f2bf(hi) << 16);
}
__device__ __forceinline__ bf16x8 cvt8(float4 a, float4 b){
    union { uint4 u; bf16x8 v; } r;
    r.u.x = (unsigned int)f2bf(a.x) | ((unsigned int)f2bf(a.y) << 16);
    r.u.y = (unsigned int)f2bf(a.z) | ((unsigned int)f2bf(a.w) << 16);
    r.u.z = (unsigned int)f2bf(b.x) | ((unsigned int)f2bf(b.y) << 16);
    r.u.w = (unsigned int)f2bf(b.z) | ((unsigned int)f2bf(b.w) << 16);
    return r.v;
}

// ---------------------------------------------------------------------------
// k0: transpose+convert weights to bf16 wT[mat][n][k] (k contiguous); zero sums.
// ---------------------------------------------------------------------------
__global__ __launch_bounds__(256) void k0_prep(
        const float* __restrict__ w_self, const float* __restrict__ w_h,
        const float* __restrict__ w_t, unsigned short* __restrict__ wT,
        float* __restrict__ sums){
    int t = blockIdx.x * 256 + threadIdx.x;
    if (t < 256*256) sums[t] = 0.f;
    if (t < 3*CH*CH){
        int mat = t / (CH*CH);
        int r = t - mat*(CH*CH);
        int k = r >> 7, n = r & 127;
        const float* w = (mat == 0) ? w_self : ((mat == 1) ? w_h : w_t);
        wT[mat*CH*CH + n*CH + k] = f2bf(w[k*CH + n]);
    }
}

// ---------------------------------------------------------------------------
// k1: H = x @ w_h, T = x @ w_t  (bf16 out, f32 MFMA accumulate). Proven in R0/R1.
// ---------------------------------------------------------------------------
__global__ __launch_bounds__(512) void k1_ht(
        const float* __restrict__ x, const unsigned short* __restrict__ wT,
        unsigned short* __restrict__ H, unsigned short* __restrict__ T, int N){
    __shared__ __align__(16) unsigned char smem[98304];
    const int tid = threadIdx.x;
    const int m0 = blockIdx.x * 128;
    #pragma unroll
    for (int i = 0; i < 8; ++i){
        int g = tid + i*512;
        int row = g >> 5, col4 = (g & 31) * 4;
        int rg = m0 + row; rg = rg < N ? rg : N-1;
        float4 v = *(const float4*)(x + (size_t)rg*CH + col4);
        unsigned int lo = (unsigned int)f2bf(v.x) | ((unsigned int)f2bf(v.y) << 16);
        unsigned int hi = (unsigned int)f2bf(v.z) | ((unsigned int)f2bf(v.w) << 16);
        unsigned int b = ((unsigned int)(row*256 + col4*2)) ^ ((unsigned int)(row & 7) << 4);
        *(uint2*)(smem + b) = make_uint2(lo, hi);
    }
    #pragma unroll
    for (int m = 0; m < 2; ++m){
        const unsigned short* src = wT + (m+1)*CH*CH;
        unsigned char* dst = smem + 32768 + m*32768;
        #pragma unroll
        for (int i = 0; i < 4; ++i){
            int g = tid + i*512;
            int n = g >> 4, k8 = (g & 15) * 8;
            uint4 v = *(const uint4*)(src + n*CH + k8);
            unsigned int b = ((unsigned int)(n*256 + k8*2)) ^ ((unsigned int)(n & 7) << 4);
            *(uint4*)(dst + b) = v;
        }
    }
    __syncthreads();
    const int lane = tid & 63, wv = tid >> 6;
    const int lr = lane & 15, lg = lane >> 4;
    f32x4 accH[8], accT[8];
    #pragma unroll
    for (int n = 0; n < 8; ++n){ accH[n] = (f32x4){0.f,0.f,0.f,0.f}; accT[n] = (f32x4){0.f,0.f,0.f,0.f}; }
    #pragma unroll
    for (int kk = 0; kk < 4; ++kk){
        int arow = wv*16 + lr;
        unsigned int ab = ((unsigned int)(arow*256 + kk*64 + lg*16)) ^ ((unsigned int)(arow & 7) << 4);
        bf16x8 a = *(const bf16x8*)(smem + ab);
        #pragma unroll
        for (int n = 0; n < 8; ++n){
            int cc = n*16 + lr;
            unsigned int bb = ((unsigned int)(cc*256 + kk*64 + lg*16)) ^ ((unsigned int)(cc & 7) << 4);
            bf16x8 bh = *(const bf16x8*)(smem + 32768 + bb);
            bf16x8 bt = *(const bf16x8*)(smem + 65536 + bb);
            accH[n] = __builtin_amdgcn_mfma_f32_16x16x32_bf16(a, bh, accH[n], 0, 0, 0);
            accT[n] = __builtin_amdgcn_mfma_f32_16x16x32_bf16(a, bt, accT[n], 0, 0, 0);
        }
    }
    #pragma unroll
    for (int n = 0; n < 8; ++n){
        int cc = n*16 + lr;
        #pragma unroll
        for (int j = 0; j < 4; ++j){
            int mr = m0 + wv*16 + lg*4 + j;
            if (mr < N){
                H[(size_t)mr*CH + cc] = f2bf(accH[n][j]);
                T[(size_t)mr*CH + cc] = f2bf(accT[n][j]);
            }
        }
    }
}

// ---------------------------------------------------------------------------
// k2 (templated): per 64-edge tile, no A/B LDS.
//   A-frags: global ea -> regs -> bf16.  B-frags: global wT (L1-hot).
//   Gather H/T rows coalesced, combine u = h+t at gather time, ONE 16KB LDS
//   buffer, ONE syncthreads. Epilogue: v = o0*(1+0.5u) + ea (L2 re-read).
//   WRITE=0: accumulate per-channel sum/sumsq partials.
//   WRITE=1: fused BN scale/shift (from sb staged in red) + ReLU -> d_out.
// ---------------------------------------------------------------------------
template<int WRITE>
__global__ __launch_bounds__(256, 5) void k2_pass(
        const float* __restrict__ ea, const int* __restrict__ eidx,
        const unsigned short* __restrict__ wT,
        const unsigned short* __restrict__ Hm, const unsigned short* __restrict__ Tm,
        float* __restrict__ out, const float* __restrict__ sb,
        float* __restrict__ sums, int E){
    __shared__ __align__(16) unsigned char smem[17408];   // U 16K + red 1K
    float* red = (float*)(smem + 16384);
    const int tid = threadIdx.x;
    const int e0 = blockIdx.x * BM;
    if (tid < 256) red[tid] = WRITE ? sb[tid] : 0.f;

    // ---- edge indices (16-lane broadcast per row) ----
    int ri4[4], ci4[4];
    #pragma unroll
    for (int i = 0; i < 4; ++i){
        int r = (tid + i*256) >> 4;
        ri4[i] = eidx[e0 + r];
        ci4[i] = eidx[E + e0 + r];
    }
    // ---- A loads: 8 x dwordx4 streaming (each byte read once per pass) ----
    const int lane = tid & 63, wv = tid >> 6;
    const int lr = lane & 15, lg = lane >> 4;
    const float* arow = ea + (size_t)(e0 + wv*16 + lr)*CH;
    float4 av[8];
    #pragma unroll
    for (int kk = 0; kk < 4; ++kk){
        av[kk*2]   = *(const float4*)(arow + kk*32 + lg*8);
        av[kk*2+1] = *(const float4*)(arow + kk*32 + lg*8 + 4);
    }
    // ---- H/T gathers: 4 random rows per instr, 256B contiguous per row ----
    uint4 hv[4], tv[4];
    #pragma unroll
    for (int i = 0; i < 4; ++i){
        int c = (tid + i*256) & 15;
        hv[i] = *(const uint4*)(Hm + (size_t)ri4[i]*CH + c*8);
        tv[i] = *(const uint4*)(Tm + (size_t)ci4[i]*CH + c*8);
    }
    // ---- convert A (frees av; gathers still in flight) ----
    bf16x8 af[4];
    #pragma unroll
    for (int kk = 0; kk < 4; ++kk) af[kk] = cvt8(av[kk*2], av[kk*2+1]);
    // ---- u = h + t -> LDS (swizzled, conflict-free epilogue read) ----
    #pragma unroll
    for (int i = 0; i < 4; ++i){
        int g = tid + i*256;
        int r = g >> 4, c = g & 15;
        uint4 u4;
        u4.x = pairadd_bf(hv[i].x, tv[i].x);
        u4.y = pairadd_bf(hv[i].y, tv[i].y);
        u4.z = pairadd_bf(hv[i].z, tv[i].z);
        u4.w = pairadd_bf(hv[i].w, tv[i].w);
        unsigned int b = ((unsigned int)(r*256 + c*16)) ^ ((unsigned int)((r >> 2) & 3) << 5);
        *(uint4*)(smem + b) = u4;
    }
    __syncthreads();                       // single barrier

    // ---- MFMA: out0 = ea_tile @ w_self, B-frags straight from L1 ----
    f32x4 acc[8];
    #pragma unroll
    for (int n = 0; n < 8; ++n) acc[n] = (f32x4){0.f,0.f,0.f,0.f};
    #pragma unroll
    for (int kk = 0; kk < 4; ++kk){
        #pragma unroll
        for (int n = 0; n < 8; ++n){
            int cc = n*16 + lr;
            bf16x8 bw = *(const bf16x8*)(wT + (size_t)cc*CH + kk*32 + lg*8);
            acc[n] = __builtin_amdgcn_mfma_f32_16x16x32_bf16(af[kk], bw, acc[n], 0, 0, 0);
        }
    }
    // ---- epilogue (C/D layout: col=lane&15, row=(lane>>4)*4+reg) ----
    #pragma unroll
    for (int n = 0; n < 8; ++n){
        int cc = n*16 + lr;
        float s = 0.f, ss = 0.f;
        #pragma unroll
        for (int j = 0; j < 4; ++j){
            int ml = wv*16 + lg*4 + j;
            unsigned int b = ((unsigned int)(ml*256 + cc*2)) ^ ((unsigned int)((ml >> 2) & 3) << 5);
            float u = bf2f(*(const unsigned short*)(smem + b));
            float r = ea[(size_t)(e0 + ml)*CH + cc];     // L2-hot (A loads touched it)
            float o0 = acc[n][j];
            float v = fmaf(o0, 0.5f*u, o0) + r;          // o0*(1+0.5(h+t)) + ea
            if (WRITE){
                out[(size_t)(e0 + ml)*CH + cc] = fmaxf(fmaf(v, red[cc], red[CH + cc]), 0.f);
            } else {
                s += v; ss += v*v;
            }
        }
        if (!WRITE){
            s  += __shfl_xor(s, 16);  s  += __shfl_xor(s, 32);
            ss += __shfl_xor(ss, 16); ss += __shfl_xor(ss, 32);
            if (lane < 16){
                atomicAdd(&red[cc], s);
                atomicAdd(&red[CH + cc], ss);
            }
        }
    }
    if (!WRITE){
        __syncthreads();
        if (tid < 256) atomicAdd(&sums[(blockIdx.x & 255)*256 + tid], red[tid]);
    }
}

// ---------------------------------------------------------------------------
// k3: reduce 256 slots -> per-channel scale/shift (sb)
// ---------------------------------------------------------------------------
__global__ __launch_bounds__(128) void k3_stats(
        const float* __restrict__ sums, const float* __restrict__ gamma,
        const float* __restrict__ beta, float* __restrict__ sb, float invE){
    int c = threadIdx.x;
    float s = 0.f, ss = 0.f;
    for (int i = 0; i < 256; ++i){ s += sums[i*256 + c]; ss += sums[i*256 + CH + c]; }
    float mean = s * invE;
    float var = ss * invE - mean*mean;     // biased variance (matches reference)
    float inv = rsqrtf(var + 1e-5f);
    float sc = gamma[c] * inv;
    sb[c] = sc;
    sb[CH + c] = beta[c] - mean * sc;
}

extern "C" void kernel_launch(void* const* d_in, const int* in_sizes, int n_in,
                              void* d_out, int out_size, void* d_ws, size_t ws_size,
                              hipStream_t stream) {
    const float* x      = (const float*)d_in[0];
    const int*   eidx   = (const int*)d_in[1];
    const float* ea     = (const float*)d_in[2];
    const float* w_self = (const float*)d_in[4];
    const float* w_h    = (const float*)d_in[5];
    const float* w_t    = (const float*)d_in[6];
    const float* gamma  = (const float*)d_in[7];
    const float* beta   = (const float*)d_in[8];
    float* out = (float*)d_out;

    const int N = in_sizes[0] / CH;     // 40000
    const int E = in_sizes[3];          // 640000

    // workspace (~21.3 MB, same footprint class R0 proved safe):
    float* sums = (float*)d_ws;                          // 256*256 f32
    float* sb   = sums + 256*256;                        // 256 f32
    unsigned short* wT = (unsigned short*)(sb + 256);    // 3*128*128 bf16
    unsigned short* H  = wT + 3*CH*CH;                   // N*128 bf16
    unsigned short* T  = H + (size_t)N*CH;               // N*128 bf16

    k0_prep<<<256, 256, 0, stream>>>(w_self, w_h, w_t, wT, sums);
    k1_ht  <<<(N + 127)/128, 512, 0, stream>>>(x, wT, H, T, N);
    k2_pass<0><<<E/BM, 256, 0, stream>>>(ea, eidx, wT, H, T, nullptr, nullptr, sums, E);
    k3_stats<<<1, 128, 0, stream>>>(sums, gamma, beta, sb, 1.0f/(float)E);
    k2_pass<1><<<E/BM, 256, 0, stream>>>(ea, eidx, wT, H, T, out, sb, nullptr, E);
}